// Round 2
// baseline (1420.789 us; speedup 1.0000x reference)
//
#include <hip/hip_runtime.h>
#include <cstdint>
#include <cstddef>

typedef __bf16 bf16;
typedef __bf16 bf16x8 __attribute__((ext_vector_type(8)));
typedef float f32x4 __attribute__((ext_vector_type(4)));

#define MFMA16(a, b, c) __builtin_amdgcn_mfma_f32_16x16x32_bf16((a), (b), (c), 0, 0, 0)

__device__ __forceinline__ float bf2f(bf16 v) { return (float)v; }

// ---- dtype-adaptive global load helpers (DT=0: bf16, DT=1: fp32) ----
template<int DT>
__device__ __forceinline__ bf16x8 g_load8(const void* base, size_t idx) {
    if constexpr (DT == 0) {
        return *(const bf16x8*)((const bf16*)base + idx);
    } else {
        const float* p = (const float*)base + idx;
        float4 a = ((const float4*)p)[0];
        float4 b = ((const float4*)p)[1];
        bf16x8 r;
        r[0] = (bf16)a.x; r[1] = (bf16)a.y; r[2] = (bf16)a.z; r[3] = (bf16)a.w;
        r[4] = (bf16)b.x; r[5] = (bf16)b.y; r[6] = (bf16)b.z; r[7] = (bf16)b.w;
        return r;
    }
}
template<int DT>
__device__ __forceinline__ float g_ld1(const void* base, size_t idx) {
    if constexpr (DT == 0) return bf2f(((const bf16*)base)[idx]);
    else                   return ((const float*)base)[idx];
}
template<int DT>
__device__ __forceinline__ void g_ld4(const void* base, size_t idx, float* o) {
    if constexpr (DT == 0) {
        uint2 d = *(const uint2*)((const bf16*)base + idx);
        const bf16* p = (const bf16*)&d;
        o[0] = bf2f(p[0]); o[1] = bf2f(p[1]); o[2] = bf2f(p[2]); o[3] = bf2f(p[3]);
    } else {
        float4 d = *(const float4*)((const float*)base + idx);
        o[0] = d.x; o[1] = d.y; o[2] = d.z; o[3] = d.w;
    }
}

// ---------------- kernel 0: dtype detect + CPB bias table + logit scales ----------------
__global__ void k_precompute(const void* __restrict__ cpb_w1, const void* __restrict__ cpb_b1,
                             const void* __restrict__ cpb_w2, const void* __restrict__ logit_scale,
                             const void* __restrict__ qkv_w_raw,
                             float* __restrict__ biasAll, float* __restrict__ scales,
                             int* __restrict__ flag)
{
    __shared__ float w1s[1024];
    __shared__ float b1s[512];
    __shared__ float w2s[2048];
    __shared__ float tabv[225][4];
    __shared__ int s_cnt;
    const int t = threadIdx.x;
    if (t == 0) s_cnt = 0;
    __syncthreads();
    // dtype detection: view qkv_w as u16; fp32-as-bf16 has ~40% wild exponents
    {
        const unsigned short* u = (const unsigned short*)qkv_w_raw;
        int c = 0;
        for (int i = t; i < 1024; i += 256) {
            const int e = (u[i] >> 7) & 0xFF;
            if (e >= 0x90 || (e != 0 && e <= 0x60)) ++c;
        }
        atomicAdd(&s_cnt, c);
    }
    __syncthreads();
    const int isf = (s_cnt > 64) ? 1 : 0;
    if (t == 0) *flag = isf;
    if (isf) {
        const float* w1 = (const float*)cpb_w1;
        const float* b1 = (const float*)cpb_b1;
        const float* w2 = (const float*)cpb_w2;
        for (int i = t; i < 1024; i += 256) w1s[i] = w1[i];
        for (int i = t; i < 512;  i += 256) b1s[i] = b1[i];
        for (int i = t; i < 2048; i += 256) w2s[i] = w2[i];
        if (t < 4) scales[t] = expf(fminf(((const float*)logit_scale)[t], 4.6051701859880914f));
    } else {
        const bf16* w1 = (const bf16*)cpb_w1;
        const bf16* b1 = (const bf16*)cpb_b1;
        const bf16* w2 = (const bf16*)cpb_w2;
        for (int i = t; i < 1024; i += 256) w1s[i] = bf2f(w1[i]);
        for (int i = t; i < 512;  i += 256) b1s[i] = bf2f(b1[i]);
        for (int i = t; i < 2048; i += 256) w2s[i] = bf2f(w2[i]);
        if (t < 4) scales[t] = expf(fminf(bf2f(((const bf16*)logit_scale)[t]), 4.6051701859880914f));
    }
    __syncthreads();
    if (t < 225) {
        const int i = t / 15, j = t % 15;
        auto relf = [](int tt) -> float {
            float tf = (float)tt * (8.0f / 7.0f);
            float a = log2f(fabsf(tf) + 1.0f) * (1.0f / 3.0f);
            return tt < 0 ? -a : a;
        };
        const float x0 = relf(i - 7), x1 = relf(j - 7);
        float a0 = 0.f, a1 = 0.f, a2 = 0.f, a3 = 0.f;
        for (int jj = 0; jj < 512; ++jj) {
            float hv = w1s[jj*2] * x0 + w1s[jj*2+1] * x1 + b1s[jj];
            hv = fmaxf(hv, 0.0f);
            a0 += w2s[jj]        * hv;
            a1 += w2s[512 + jj]  * hv;
            a2 += w2s[1024 + jj] * hv;
            a3 += w2s[1536 + jj] * hv;
        }
        tabv[t][0] = a0; tabv[t][1] = a1; tabv[t][2] = a2; tabv[t][3] = a3;
    }
    __syncthreads();
    for (int idx = t; idx < 4*64*64; idx += 256) {
        const int h = idx >> 12, rem = idx & 4095, i = rem >> 6, j = rem & 63;
        const int di = (i >> 3) - (j >> 3) + 7;
        const int dj = (i & 7) - (j & 7) + 7;
        const float bv = tabv[di*15 + dj][h];
        biasAll[idx] = 16.0f / (1.0f + expf(-bv));
    }
}

// ---------------- kernel 1: windowed attention + proj + LN + residual ----------------
// one block per (batch, window): 4096 blocks, 256 threads (wave w = head w)
template<int DT>
__global__ __launch_bounds__(256, 1) void k_attn(
    const void* __restrict__ x, const void* __restrict__ qkv_w,
    const void* __restrict__ q_bias, const void* __restrict__ v_bias,
    const void* __restrict__ proj_w, const void* __restrict__ proj_b,
    const void* __restrict__ n1w, const void* __restrict__ n1b,
    const float* __restrict__ biasAll, const float* __restrict__ scales,
    const int* __restrict__ flag, bf16* __restrict__ x1out)
{
    if (*flag != DT) return;

    __shared__ bf16 Xs[64*136];      // window input (== residual shortcut), pad 136
    __shared__ bf16 qkvs[64*264];    // q (cols 0..127) and k (cols 128..255), pad 264
    __shared__ bf16 vs[128*72];      // v transposed: vs[c][token], pad 72
    __shared__ bf16 Ps[4*64*72];     // per-wave softmax P; later reused as x1 staging
    __shared__ bf16 Os[64*136];      // attention output (concat heads), pad 136
    __shared__ float invqs[4*64];
    __shared__ float invks[4*64];
    __shared__ int   rid[64];

    const int tid  = threadIdx.x;
    const int wv   = tid >> 6;
    const int lane = tid & 63;
    const int l15  = lane & 15;
    const int quad = lane >> 4;

    const int bid = blockIdx.x;
    const int b   = bid >> 8;
    const int wh  = (bid >> 4) & 15;
    const int ww  = bid & 15;

    // ---- stage 0: gather shifted window into Xs[token][c]; region ids ----
    {
        const int c  = tid & 127;
        const int rb = tid >> 7;
        const int w0 = ww*8 + 4;
        const int w1 = (ww*8 + 8) & 127;
#pragma unroll
        for (int k = 0; k < 4; ++k) {
            const int r    = k*2 + rb;
            const int srch = (wh*8 + r + 4) & 127;
            const size_t rowbase = (((size_t)(b*128 + c))*128 + srch)*128;
            float va[4], vb[4];
            g_ld4<DT>(x, rowbase + w0, va);
            g_ld4<DT>(x, rowbase + w1, vb);
#pragma unroll
            for (int j = 0; j < 4; ++j) {
                Xs[(r*8 + j)*136 + c]     = (bf16)va[j];
                Xs[(r*8 + 4 + j)*136 + c] = (bf16)vb[j];
            }
        }
        if (tid < 64) {
            const int rr = tid >> 3, cc = tid & 7;
            const int hs = wh*8 + rr, wsc = ww*8 + cc;
            const int rh = (hs  < 120) ? 0 : ((hs  < 124) ? 1 : 2);
            const int rw = (wsc < 120) ? 0 : ((wsc < 124) ? 1 : 2);
            rid[tid] = rh*3 + rw;
        }
    }
    __syncthreads();

    // ---- stage 1: qkv = Xs @ qkv_w^T + bias; q,k -> qkvs; v -> vs (transposed) ----
    {
        f32x4 acc[4][6];
#pragma unroll
        for (int mt = 0; mt < 4; ++mt)
#pragma unroll
            for (int nl = 0; nl < 6; ++nl) acc[mt][nl] = (f32x4){0.f, 0.f, 0.f, 0.f};
#pragma unroll
        for (int ks = 0; ks < 4; ++ks) {
            bf16x8 a[4];
#pragma unroll
            for (int mt = 0; mt < 4; ++mt)
                a[mt] = *(const bf16x8*)&Xs[(mt*16 + l15)*136 + ks*32 + quad*8];
#pragma unroll
            for (int nl = 0; nl < 6; ++nl) {
                const int o = (wv*6 + nl)*16 + l15;
                bf16x8 bw = g_load8<DT>(qkv_w, (size_t)o*128 + ks*32 + quad*8);
#pragma unroll
                for (int mt = 0; mt < 4; ++mt)
                    acc[mt][nl] = MFMA16(a[mt], bw, acc[mt][nl]);
            }
        }
#pragma unroll
        for (int nl = 0; nl < 6; ++nl) {
            const int col = (wv*6 + nl)*16 + l15;
            const float bias = (col < 128) ? g_ld1<DT>(q_bias, col)
                              : ((col < 256) ? 0.0f : g_ld1<DT>(v_bias, col - 256));
#pragma unroll
            for (int mt = 0; mt < 4; ++mt)
#pragma unroll
                for (int r = 0; r < 4; ++r) {
                    const int row = mt*16 + quad*4 + r;
                    const float v = acc[mt][nl][r] + bias;
                    if (col < 256) qkvs[row*264 + col] = (bf16)v;       // tile-uniform branch
                    else           vs[(col - 256)*72 + row] = (bf16)v;
                }
        }
    }
    __syncthreads();

    // ---- stage 2: per-head q/k row L2 norms (wave = head, lane = token) ----
    {
        const int n = lane;
        const bf16* qrow = &qkvs[n*264 + wv*32];
        const bf16* krow = &qkvs[n*264 + 128 + wv*32];
        float sq = 0.f, sk = 0.f;
#pragma unroll
        for (int dd = 0; dd < 4; ++dd) {
            bf16x8 vq = *(const bf16x8*)(qrow + dd*8);
            bf16x8 vk = *(const bf16x8*)(krow + dd*8);
#pragma unroll
            for (int e = 0; e < 8; ++e) {
                const float fq = (float)vq[e]; sq += fq*fq;
                const float fk = (float)vk[e]; sk += fk*fk;
            }
        }
        invqs[wv*64 + n] = 1.0f / fmaxf(sqrtf(sq), 1e-12f);
        invks[wv*64 + n] = 1.0f / fmaxf(sqrtf(sk), 1e-12f);
    }
    __syncthreads();

    // ---- stage 3: S = scale*(q.k)*invq*invk + bias + mask; softmax; P -> LDS ----
    {
        const float scale = scales[wv];
        f32x4 s[4][4];
#pragma unroll
        for (int mt = 0; mt < 4; ++mt)
#pragma unroll
            for (int nt = 0; nt < 4; ++nt) s[mt][nt] = (f32x4){0.f, 0.f, 0.f, 0.f};
        bf16x8 aq[4];
#pragma unroll
        for (int mt = 0; mt < 4; ++mt)
            aq[mt] = *(const bf16x8*)&qkvs[(mt*16 + l15)*264 + wv*32 + quad*8];
#pragma unroll
        for (int nt = 0; nt < 4; ++nt) {
            bf16x8 bk = *(const bf16x8*)&qkvs[(nt*16 + l15)*264 + 128 + wv*32 + quad*8];
#pragma unroll
            for (int mt = 0; mt < 4; ++mt)
                s[mt][nt] = MFMA16(aq[mt], bk, s[mt][nt]);
        }
        const float* bg = biasAll + wv*4096;
        const bool bnd = (wh == 15) || (ww == 15);
        float ikj[4]; int rj[4];
#pragma unroll
        for (int nt = 0; nt < 4; ++nt) {
            ikj[nt] = invks[wv*64 + nt*16 + l15];
            rj[nt]  = rid[nt*16 + l15];
        }
#pragma unroll
        for (int mt = 0; mt < 4; ++mt)
#pragma unroll
            for (int r = 0; r < 4; ++r) {
                const int i = mt*16 + quad*4 + r;
                const float iqs = invqs[wv*64 + i] * scale;
                const int ri = rid[i];
#pragma unroll
                for (int nt = 0; nt < 4; ++nt) {
                    const int j = nt*16 + l15;
                    float v = s[mt][nt][r] * (iqs * ikj[nt]) + bg[i*64 + j];
                    if (bnd && (ri != rj[nt])) v -= 100.0f;
                    s[mt][nt][r] = v;
                }
            }
        // softmax over j (16 lanes of the quad x 4 n-tiles)
#pragma unroll
        for (int mt = 0; mt < 4; ++mt) {
            float mx[4], sm[4];
#pragma unroll
            for (int r = 0; r < 4; ++r) {
                float m = fmaxf(fmaxf(s[mt][0][r], s[mt][1][r]), fmaxf(s[mt][2][r], s[mt][3][r]));
                m = fmaxf(m, __shfl_xor(m, 1));
                m = fmaxf(m, __shfl_xor(m, 2));
                m = fmaxf(m, __shfl_xor(m, 4));
                m = fmaxf(m, __shfl_xor(m, 8));
                mx[r] = m; sm[r] = 0.f;
            }
#pragma unroll
            for (int nt = 0; nt < 4; ++nt)
#pragma unroll
                for (int r = 0; r < 4; ++r) {
                    const float e = __expf(s[mt][nt][r] - mx[r]);
                    s[mt][nt][r] = e;
                    sm[r] += e;
                }
#pragma unroll
            for (int r = 0; r < 4; ++r) {
                float t2 = sm[r];
                t2 += __shfl_xor(t2, 1);
                t2 += __shfl_xor(t2, 2);
                t2 += __shfl_xor(t2, 4);
                t2 += __shfl_xor(t2, 8);
                sm[r] = 1.0f / t2;
            }
#pragma unroll
            for (int nt = 0; nt < 4; ++nt)
#pragma unroll
                for (int r = 0; r < 4; ++r) {
                    const float p = s[mt][nt][r] * sm[r];
                    Ps[wv*64*72 + (mt*16 + quad*4 + r)*72 + nt*16 + l15] = (bf16)p;
                }
        }
    }
    __syncthreads();

    // ---- stage 4: O = P @ V -> Os ----
    {
        f32x4 o[4][2];
#pragma unroll
        for (int mt = 0; mt < 4; ++mt)
#pragma unroll
            for (int nt = 0; nt < 2; ++nt) o[mt][nt] = (f32x4){0.f, 0.f, 0.f, 0.f};
#pragma unroll
        for (int ks = 0; ks < 2; ++ks) {
            bf16x8 ap[4];
#pragma unroll
            for (int mt = 0; mt < 4; ++mt)
                ap[mt] = *(const bf16x8*)&Ps[wv*64*72 + (mt*16 + l15)*72 + ks*32 + quad*8];
#pragma unroll
            for (int nt = 0; nt < 2; ++nt) {
                bf16x8 bv = *(const bf16x8*)&vs[(wv*32 + nt*16 + l15)*72 + ks*32 + quad*8];
#pragma unroll
                for (int mt = 0; mt < 4; ++mt)
                    o[mt][nt] = MFMA16(ap[mt], bv, o[mt][nt]);
            }
        }
#pragma unroll
        for (int mt = 0; mt < 4; ++mt)
#pragma unroll
            for (int nt = 0; nt < 2; ++nt)
#pragma unroll
                for (int r = 0; r < 4; ++r) {
                    const int i = mt*16 + quad*4 + r;
                    Os[i*136 + wv*32 + nt*16 + l15] = (bf16)o[mt][nt][r];
                }
    }
    __syncthreads();

    // ---- stage 5: proj + LN(norm1) + residual(Xs) -> x1 staging (reuse Ps) ----
    {
        f32x4 pa[8];
#pragma unroll
        for (int nt = 0; nt < 8; ++nt) pa[nt] = (f32x4){0.f, 0.f, 0.f, 0.f};
#pragma unroll
        for (int ks = 0; ks < 4; ++ks) {
            bf16x8 ao = *(const bf16x8*)&Os[(wv*16 + l15)*136 + ks*32 + quad*8];
#pragma unroll
            for (int nt = 0; nt < 8; ++nt) {
                bf16x8 bw = g_load8<DT>(proj_w, (size_t)(nt*16 + l15)*128 + ks*32 + quad*8);
                pa[nt] = MFMA16(ao, bw, pa[nt]);
            }
        }
        float pb[8], wn[8], bn[8];
#pragma unroll
        for (int nt = 0; nt < 8; ++nt) {
            const int colc = nt*16 + l15;
            pb[nt] = g_ld1<DT>(proj_b, colc);
            wn[nt] = g_ld1<DT>(n1w, colc);
            bn[nt] = g_ld1<DT>(n1b, colc);
        }
        bf16* x1s = Ps;  // Ps is dead past this barrier
#pragma unroll
        for (int r = 0; r < 4; ++r) {
            const int i = wv*16 + quad*4 + r;
            float vals[8]; float sum = 0.f;
#pragma unroll
            for (int nt = 0; nt < 8; ++nt) { vals[nt] = pa[nt][r] + pb[nt]; sum += vals[nt]; }
            sum += __shfl_xor(sum, 1); sum += __shfl_xor(sum, 2);
            sum += __shfl_xor(sum, 4); sum += __shfl_xor(sum, 8);
            const float mu = sum * (1.0f/128.0f);
            float var = 0.f;
#pragma unroll
            for (int nt = 0; nt < 8; ++nt) { const float d = vals[nt] - mu; var += d*d; }
            var += __shfl_xor(var, 1); var += __shfl_xor(var, 2);
            var += __shfl_xor(var, 4); var += __shfl_xor(var, 8);
            const float rstd = rsqrtf(var * (1.0f/128.0f) + 1e-5f);
#pragma unroll
            for (int nt = 0; nt < 8; ++nt) {
                const int colc = nt*16 + l15;
                const float y = (vals[nt] - mu) * rstd * wn[nt] + bn[nt];
                const float x1v = bf2f(Xs[i*136 + colc]) + y;
                x1s[i*136 + colc] = (bf16)x1v;
            }
        }
    }
    __syncthreads();

    // ---- stage 6: write x1 tile to global (reverse-shifted final positions) ----
    {
        const bf16* x1s = Ps;
        const int n = tid >> 2, part = tid & 3;
        const int rr = n >> 3, cc = n & 7;
        const int hf = (wh*8 + rr + 4) & 127;
        const int wf = (ww*8 + cc + 4) & 127;
        bf16* dst = x1out + ((size_t)b*16384 + hf*128 + wf)*128 + part*32;
        const uint4* srcq = (const uint4*)&x1s[n*136 + part*32];
#pragma unroll
        for (int k2 = 0; k2 < 4; ++k2)
            ((uint4*)dst)[k2] = srcq[k2];
    }
}

// ---------------- kernel 2: MLP + LN(norm2) + residual, planar output ----------------
// 4096 blocks x 64 tokens, 256 threads
template<int DT>
__global__ __launch_bounds__(256, 2) void k_mlp(
    const bf16* __restrict__ x1, const void* __restrict__ fc1w, const void* __restrict__ fc1b,
    const void* __restrict__ fc2w, const void* __restrict__ fc2b,
    const void* __restrict__ n2w, const void* __restrict__ n2b,
    const int* __restrict__ flag, void* __restrict__ out)
{
    if (*flag != DT) return;

    __shared__ bf16 x1s[64*136];
    __shared__ bf16 hs[64*264];   // one 256-wide hidden chunk; reused as x2 staging

    const int tid  = threadIdx.x;
    const int wv   = tid >> 6;
    const int lane = tid & 63;
    const int l15  = lane & 15;
    const int quad = lane >> 4;
    const int bid  = blockIdx.x;

    {
        const int n = tid >> 2, part = tid & 3;
        const uint4* src = (const uint4*)(x1 + ((size_t)bid*64 + n)*128 + part*32);
        uint4* dst = (uint4*)&x1s[n*136 + part*32];
#pragma unroll
        for (int k = 0; k < 4; ++k) dst[k] = src[k];
    }
    __syncthreads();

    f32x4 ya[8];
#pragma unroll
    for (int nt = 0; nt < 8; ++nt) ya[nt] = (f32x4){0.f, 0.f, 0.f, 0.f};

#pragma unroll
    for (int ch = 0; ch < 2; ++ch) {
        if (ch) __syncthreads();   // previous chunk's fc2 reads of hs must finish
        // fc1 chunk: all 64 tokens x 256 hidden (wave w owns 64 hidden cols)
        f32x4 ha[4][4];
#pragma unroll
        for (int mt = 0; mt < 4; ++mt)
#pragma unroll
            for (int nt = 0; nt < 4; ++nt) ha[mt][nt] = (f32x4){0.f, 0.f, 0.f, 0.f};
#pragma unroll
        for (int ks = 0; ks < 4; ++ks) {
            bf16x8 a[4];
#pragma unroll
            for (int mt = 0; mt < 4; ++mt)
                a[mt] = *(const bf16x8*)&x1s[(mt*16 + l15)*136 + ks*32 + quad*8];
#pragma unroll
            for (int nt = 0; nt < 4; ++nt) {
                const int hid = ch*256 + wv*64 + nt*16 + l15;
                bf16x8 bw = g_load8<DT>(fc1w, (size_t)hid*128 + ks*32 + quad*8);
#pragma unroll
                for (int mt = 0; mt < 4; ++mt)
                    ha[mt][nt] = MFMA16(a[mt], bw, ha[mt][nt]);
            }
        }
#pragma unroll
        for (int nt = 0; nt < 4; ++nt) {
            const int hid = ch*256 + wv*64 + nt*16 + l15;
            const float bb = g_ld1<DT>(fc1b, hid);
            const int hl = wv*64 + nt*16 + l15;
#pragma unroll
            for (int mt = 0; mt < 4; ++mt)
#pragma unroll
                for (int r = 0; r < 4; ++r) {
                    float v = ha[mt][nt][r] + bb;
                    v = v / (1.0f + __expf(-v));   // silu
                    hs[(mt*16 + quad*4 + r)*264 + hl] = (bf16)v;
                }
        }
        __syncthreads();
        // fc2 partial: wave w owns token rows w*16..w*16+15, all 128 outputs
#pragma unroll
        for (int ks = 0; ks < 8; ++ks) {
            bf16x8 ah = *(const bf16x8*)&hs[(wv*16 + l15)*264 + ks*32 + quad*8];
#pragma unroll
            for (int nt = 0; nt < 8; ++nt) {
                bf16x8 bw = g_load8<DT>(fc2w, (size_t)(nt*16 + l15)*512 + ch*256 + ks*32 + quad*8);
                ya[nt] = MFMA16(ah, bw, ya[nt]);
            }
        }
    }
    __syncthreads();   // all fc2 reads of hs done before reuse as x2 staging

    {
        float pb[8], wn[8], bn[8];
#pragma unroll
        for (int nt = 0; nt < 8; ++nt) {
            const int colc = nt*16 + l15;
            pb[nt] = g_ld1<DT>(fc2b, colc);
            wn[nt] = g_ld1<DT>(n2w, colc);
            bn[nt] = g_ld1<DT>(n2b, colc);
        }
        bf16* x2s = hs;
#pragma unroll
        for (int r = 0; r < 4; ++r) {
            const int i = wv*16 + quad*4 + r;
            float vals[8]; float sum = 0.f;
#pragma unroll
            for (int nt = 0; nt < 8; ++nt) { vals[nt] = ya[nt][r] + pb[nt]; sum += vals[nt]; }
            sum += __shfl_xor(sum, 1); sum += __shfl_xor(sum, 2);
            sum += __shfl_xor(sum, 4); sum += __shfl_xor(sum, 8);
            const float mu = sum * (1.0f/128.0f);
            float var = 0.f;
#pragma unroll
            for (int nt = 0; nt < 8; ++nt) { const float d = vals[nt] - mu; var += d*d; }
            var += __shfl_xor(var, 1); var += __shfl_xor(var, 2);
            var += __shfl_xor(var, 4); var += __shfl_xor(var, 8);
            const float rstd = rsqrtf(var * (1.0f/128.0f) + 1e-5f);
#pragma unroll
            for (int nt = 0; nt < 8; ++nt) {
                const int colc = nt*16 + l15;
                const float yv = (vals[nt] - mu) * rstd * wn[nt] + bn[nt];
                const float x2v = bf2f(x1s[i*136 + colc]) + yv;
                x2s[i*136 + colc] = (bf16)x2v;
            }
        }
    }
    __syncthreads();

    // transpose-out: (token, c) -> planar (B, C, H, W), coalesced stores
    {
        const int c = tid >> 1, half = tid & 1;
        const int b = bid >> 8, rem = bid & 255;
        const int hh = rem >> 1, w0 = (rem & 1)*64;
        const bf16* x2s = hs;
        const size_t base_off = ((size_t)(b*128 + c))*16384 + hh*128 + w0 + half*32;
        if constexpr (DT == 0) {
            const unsigned short* x2u = (const unsigned short*)hs;
            bf16* dst = (bf16*)out + base_off;
#pragma unroll
            for (int g = 0; g < 4; ++g) {
                const int tb = half*32 + g*8;
                uint4 u;
                u.x = (unsigned)x2u[(tb+0)*136 + c] | ((unsigned)x2u[(tb+1)*136 + c] << 16);
                u.y = (unsigned)x2u[(tb+2)*136 + c] | ((unsigned)x2u[(tb+3)*136 + c] << 16);
                u.z = (unsigned)x2u[(tb+4)*136 + c] | ((unsigned)x2u[(tb+5)*136 + c] << 16);
                u.w = (unsigned)x2u[(tb+6)*136 + c] | ((unsigned)x2u[(tb+7)*136 + c] << 16);
                ((uint4*)dst)[g] = u;
            }
        } else {
            float* dst = (float*)out + base_off;
#pragma unroll
            for (int g = 0; g < 4; ++g) {
                const int tb = half*32 + g*8;
                float4 u0, u1;
                u0.x = bf2f(x2s[(tb+0)*136 + c]); u0.y = bf2f(x2s[(tb+1)*136 + c]);
                u0.z = bf2f(x2s[(tb+2)*136 + c]); u0.w = bf2f(x2s[(tb+3)*136 + c]);
                u1.x = bf2f(x2s[(tb+4)*136 + c]); u1.y = bf2f(x2s[(tb+5)*136 + c]);
                u1.z = bf2f(x2s[(tb+6)*136 + c]); u1.w = bf2f(x2s[(tb+7)*136 + c]);
                ((float4*)dst)[2*g]     = u0;
                ((float4*)dst)[2*g + 1] = u1;
            }
        }
    }
}

extern "C" void kernel_launch(void* const* d_in, const int* in_sizes, int n_in,
                              void* d_out, int out_size, void* d_ws, size_t ws_size,
                              hipStream_t stream)
{
    (void)in_sizes; (void)n_in; (void)out_size; (void)ws_size;
    const void* x      = d_in[0];
    const void* n1w    = d_in[1];
    const void* n1b    = d_in[2];
    const void* qkv_w  = d_in[3];
    const void* q_bias = d_in[4];
    const void* v_bias = d_in[5];
    const void* lscale = d_in[6];
    const void* cpb_w1 = d_in[7];
    const void* cpb_b1 = d_in[8];
    const void* cpb_w2 = d_in[9];
    const void* proj_w = d_in[10];
    const void* proj_b = d_in[11];
    const void* n2w    = d_in[12];
    const void* n2b    = d_in[13];
    const void* fc1w   = d_in[14];
    const void* fc1b   = d_in[15];
    const void* fc2w   = d_in[16];
    const void* fc2b   = d_in[17];

    float* biasAll = (float*)d_ws;                          // 4*64*64 f32 = 64 KiB @ 0
    float* scales  = (float*)((char*)d_ws + 65536);         // 4 f32
    int*   flag    = (int*)((char*)d_ws + 65552);           // dtype flag
    bf16*  x1buf   = (bf16*)((char*)d_ws + 131072);         // 16*16384*128 bf16 = 64 MiB

    k_precompute<<<dim3(1), dim3(256), 0, stream>>>(cpb_w1, cpb_b1, cpb_w2, lscale, qkv_w,
                                                    biasAll, scales, flag);
    k_attn<0><<<dim3(4096), dim3(256), 0, stream>>>(x, qkv_w, q_bias, v_bias, proj_w, proj_b,
                                                    n1w, n1b, biasAll, scales, flag, x1buf);
    k_attn<1><<<dim3(4096), dim3(256), 0, stream>>>(x, qkv_w, q_bias, v_bias, proj_w, proj_b,
                                                    n1w, n1b, biasAll, scales, flag, x1buf);
    k_mlp<0><<<dim3(4096), dim3(256), 0, stream>>>(x1buf, fc1w, fc1b, fc2w, fc2b, n2w, n2b, flag, d_out);
    k_mlp<1><<<dim3(4096), dim3(256), 0, stream>>>(x1buf, fc1w, fc1b, fc2w, fc2b, n2w, n2b, flag, d_out);
}